// Round 1
// baseline (135.272 us; speedup 1.0000x reference)
//
#include <hip/hip_runtime.h>
#include <hip/hip_bf16.h>
#include <math.h>

#define H 256
#define L_SEQ 131072
#define IN_DIM 50

__device__ __forceinline__ float wave_reduce_sum(float v) {
#pragma unroll
  for (int off = 32; off > 0; off >>= 1) v += __shfl_xor(v, off, 64);
  return v;
}
__device__ __forceinline__ float wave_reduce_max(float v) {
#pragma unroll
  for (int off = 32; off > 0; off >>= 1) v = fmaxf(v, __shfl_xor(v, off, 64));
  return v;
}

// ---------------- K1: one-pass online-softmax attention, per-block partials ----
__global__ __launch_bounds__(256) void k1_attn_partial(
    const float* __restrict__ E, const float* __restrict__ h,
    float* __restrict__ part, int rows_per_block) {
  const int b = blockIdx.x;
  const int w = threadIdx.x >> 6;
  const int lane = threadIdx.x & 63;
  const float4 hreg = reinterpret_cast<const float4*>(h)[lane];
  float m = -3.0e38f, s = 0.f;
  float4 acc = make_float4(0.f, 0.f, 0.f, 0.f);
  const int base = b * rows_per_block;
  for (int r = w; r < rows_per_block; r += 4) {
    const float4 e = reinterpret_cast<const float4*>(E)[(size_t)(base + r) * 64 + lane];
    float d = e.x * hreg.x + e.y * hreg.y + e.z * hreg.z + e.w * hreg.w;
    d = wave_reduce_sum(d);              // score, uniform across wave
    if (d > m) {                         // wave-uniform branch
      const float sc = __expf(m - d);
      s = s * sc + 1.f;
      acc.x = acc.x * sc + e.x;
      acc.y = acc.y * sc + e.y;
      acc.z = acc.z * sc + e.z;
      acc.w = acc.w * sc + e.w;
      m = d;
    } else {
      const float wt = __expf(d - m);
      s += wt;
      acc.x += wt * e.x; acc.y += wt * e.y; acc.z += wt * e.z; acc.w += wt * e.w;
    }
  }
  __shared__ float sm[4], ss[4];
  __shared__ float sacc[4][H];
  sacc[w][4 * lane + 0] = acc.x;
  sacc[w][4 * lane + 1] = acc.y;
  sacc[w][4 * lane + 2] = acc.z;
  sacc[w][4 * lane + 3] = acc.w;
  if (lane == 0) { sm[w] = m; ss[w] = s; }
  __syncthreads();
  const int t = threadIdx.x;
  const float M = fmaxf(fmaxf(sm[0], sm[1]), fmaxf(sm[2], sm[3]));
  const float e0 = __expf(sm[0] - M), e1 = __expf(sm[1] - M);
  const float e2 = __expf(sm[2] - M), e3 = __expf(sm[3] - M);
  const float ctx = e0 * sacc[0][t] + e1 * sacc[1][t] + e2 * sacc[2][t] + e3 * sacc[3][t];
  float* pb = part + (size_t)b * 258;
  pb[2 + t] = ctx;
  if (t == 0) { pb[0] = M; pb[1] = e0 * ss[0] + e1 * ss[1] + e2 * ss[2] + e3 * ss[3]; }
}

// ---------------- K2: combine partials -> ctx, attn proj, embeddings, x[50] ----
__global__ __launch_bounds__(1024) void k2_combine(
    const float* __restrict__ part, int nblk,
    const float* __restrict__ chord_emb, const float* __restrict__ pitch_emb,
    const float* __restrict__ dur_emb,
    const float* __restrict__ attn_W, const float* __restrict__ attn_b,
    const int* __restrict__ sec_p, const int* __restrict__ chord_p,
    const int* __restrict__ tp_p, const int* __restrict__ note_p,
    float* __restrict__ x_ws, float* __restrict__ etrue_ws) {
  const int t = threadIdx.x;
  const int lane = t & 63, w = t >> 6;  // 16 waves
  __shared__ float red[16];
  __shared__ float Msh, Ssh;
  __shared__ float ctxq[4][H];
  __shared__ float ctx_s[H];
  // global max
  float lm = -3.0e38f;
  for (int b = t; b < nblk; b += 1024) lm = fmaxf(lm, part[(size_t)b * 258]);
  lm = wave_reduce_max(lm);
  if (lane == 0) red[w] = lm;
  __syncthreads();
  if (t == 0) {
    float M = red[0];
    for (int i = 1; i < 16; i++) M = fmaxf(M, red[i]);
    Msh = M;
  }
  __syncthreads();
  const float M = Msh;
  // global denom
  float ls = 0.f;
  for (int b = t; b < nblk; b += 1024)
    ls += __expf(part[(size_t)b * 258] - M) * part[(size_t)b * 258 + 1];
  ls = wave_reduce_sum(ls);
  if (lane == 0) red[w] = ls;
  __syncthreads();
  if (t == 0) {
    float S = 0.f;
    for (int i = 0; i < 16; i++) S += red[i];
    Ssh = S;
  }
  __syncthreads();
  const float Sinv = 1.f / Ssh;
  // weighted ctx combine: 4 b-stripes x 256 columns
  const int col = t & 255, q = t >> 8;
  float lc = 0.f;
  for (int b = q; b < nblk; b += 4) {
    const float* pb = part + (size_t)b * 258;
    lc += __expf(pb[0] - M) * pb[2 + col];
  }
  ctxq[q][col] = lc;
  __syncthreads();
  if (t < H) ctx_s[t] = (ctxq[0][t] + ctxq[1][t] + ctxq[2][t] + ctxq[3][t]) * Sinv;
  __syncthreads();
  // ctx10 = attn_W @ ctx + attn_b  (waves 0..9, one row each)
  if (w < 10) {
    const float4 c4 = reinterpret_cast<const float4*>(ctx_s)[lane];
    const float4 a4 = reinterpret_cast<const float4*>(attn_W + w * H)[lane];
    float d = c4.x * a4.x + c4.y * a4.y + c4.z * a4.z + c4.w * a4.w;
    d = wave_reduce_sum(d);
    if (lane == 0) x_ws[40 + w] = d + attn_b[w];
  }
  // embedding gathers: x = [e_pitch, e_dur, e_chord, e_sec, ctx10]
  if (t < 10)       x_ws[t] = pitch_emb[note_p[0] * 10 + t];
  else if (t < 20)  x_ws[t] = dur_emb[note_p[1] * 10 + (t - 10)];
  else if (t < 30)  x_ws[t] = chord_emb[chord_p[0] * 10 + (t - 20)];
  else if (t < 40)  x_ws[t] = chord_emb[sec_p[0] * 10 + (t - 30)];
  else if (t < 50)  etrue_ws[t - 40] = pitch_emb[tp_p[0] * 10 + (t - 40)];
}

// ---------------- K3: gates = W_ih@x + W_hh@h + b_ih + b_hh ----
__global__ __launch_bounds__(256) void k3_gates(
    const float* __restrict__ W_ih, const float* __restrict__ W_hh,
    const float* __restrict__ b_ih, const float* __restrict__ b_hh,
    const float* __restrict__ h, const float* __restrict__ x_ws,
    float* __restrict__ gates_ws) {
  __shared__ float x_s[IN_DIM];
  const int t = threadIdx.x;
  if (t < IN_DIM) x_s[t] = x_ws[t];
  __syncthreads();
  const int lane = t & 63, w = t >> 6;
  const float4 hreg = reinterpret_cast<const float4*>(h)[lane];
  const int row0 = blockIdx.x * 32 + w * 8;
#pragma unroll
  for (int i = 0; i < 8; i++) {
    const int row = row0 + i;
    const float4 wv = reinterpret_cast<const float4*>(W_hh + (size_t)row * H)[lane];
    float d = wv.x * hreg.x + wv.y * hreg.y + wv.z * hreg.z + wv.w * hreg.w;
    if (lane < IN_DIM) d += W_ih[row * IN_DIM + lane] * x_s[lane];
    d = wave_reduce_sum(d);
    if (lane == 0) gates_ws[row] = d + b_ih[row] + b_hh[row];
  }
}

// ---------------- K4: LSTM nonlinearity + both heads + outputs ----
__global__ __launch_bounds__(256) void k4_final(
    const float* __restrict__ gates_ws, const float* __restrict__ c_in,
    const float* __restrict__ pitch_W, const float* __restrict__ pitch_b,
    const float* __restrict__ dur_W, const float* __restrict__ dur_b,
    const float* __restrict__ etrue_ws, float* __restrict__ out) {
  __shared__ float hs[H];
  __shared__ float et[16];
  const int t = threadIdx.x;
  {
    const float ig = gates_ws[t], fg = gates_ws[256 + t];
    const float gg = gates_ws[512 + t], og = gates_ws[768 + t];
    const float i_s = 1.f / (1.f + __expf(-ig));
    const float f_s = 1.f / (1.f + __expf(-fg));
    const float g_t = tanhf(gg);
    const float o_s = 1.f / (1.f + __expf(-og));
    const float cn = f_s * c_in[t] + i_s * g_t;
    const float hn = o_s * tanhf(cn);
    out[79 + t] = hn;        // h_new at [79, 335)
    out[335 + t] = cn;       // c_new at [335, 591)
    hs[t] = hn;
  }
  if (t < 10) et[t] = etrue_ws[t];
  __syncthreads();
  const int lane = t & 63, w = t >> 6;
  const float4 h4 = reinterpret_cast<const float4*>(hs)[lane];
  // pitch head: 63 rows
  for (int row = w; row < 63; row += 4) {
    const float4 pw = reinterpret_cast<const float4*>(pitch_W + (size_t)row * H)[lane];
    float d = pw.x * h4.x + pw.y * h4.y + pw.z * h4.z + pw.w * h4.w;
    d = wave_reduce_sum(d);
    if (lane == 0) out[row] = d + pitch_b[row];
  }
  // dur head: 16 rows over concat([e_true, h_new]) (266)
  for (int row = w; row < 16; row += 4) {
    const float* dw = dur_W + (size_t)row * 266;
    float d = 0.f;
    for (int k = lane; k < 266; k += 64)
      d += dw[k] * (k < 10 ? et[k] : hs[k - 10]);
    d = wave_reduce_sum(d);
    if (lane == 0) out[63 + row] = d + dur_b[row];
  }
}

extern "C" void kernel_launch(void* const* d_in, const int* in_sizes, int n_in,
                              void* d_out, int out_size, void* d_ws, size_t ws_size,
                              hipStream_t stream) {
  const int* sec       = (const int*)d_in[0];
  const int* chord     = (const int*)d_in[1];
  const int* tp        = (const int*)d_in[2];
  const int* note      = (const int*)d_in[3];
  const float* hn      = (const float*)d_in[4];
  const float* cn      = (const float*)d_in[5];
  const float* E       = (const float*)d_in[6];
  const float* chord_e = (const float*)d_in[7];
  const float* pitch_e = (const float*)d_in[8];
  const float* dur_e   = (const float*)d_in[9];
  const float* W_ih    = (const float*)d_in[10];
  const float* W_hh    = (const float*)d_in[11];
  const float* b_ih    = (const float*)d_in[12];
  const float* b_hh    = (const float*)d_in[13];
  const float* pitch_W = (const float*)d_in[14];
  const float* pitch_b = (const float*)d_in[15];
  const float* dur_W   = (const float*)d_in[16];
  const float* dur_b   = (const float*)d_in[17];
  const float* attn_W  = (const float*)d_in[18];
  const float* attn_b  = (const float*)d_in[19];
  float* out = (float*)d_out;
  float* ws = (float*)d_ws;

  // pick K1 block count (power of two so rows divide evenly), bounded by ws
  int nblk = 1024;
  while (nblk > 64 && (size_t)(nblk * 258 + 2048) * sizeof(float) > ws_size) nblk >>= 1;
  const int rpb = L_SEQ / nblk;

  float* part = ws;                        // nblk * 258
  float* x_ws = ws + (size_t)nblk * 258;   // 50 (+pad)
  float* etrue_ws = x_ws + 64;             // 10
  float* gates_ws = x_ws + 128;            // 1024

  k1_attn_partial<<<nblk, 256, 0, stream>>>(E, hn, part, rpb);
  k2_combine<<<1, 1024, 0, stream>>>(part, nblk, chord_e, pitch_e, dur_e,
                                     attn_W, attn_b, sec, chord, tp, note,
                                     x_ws, etrue_ws);
  k3_gates<<<32, 256, 0, stream>>>(W_ih, W_hh, b_ih, b_hh, hn, x_ws, gates_ws);
  k4_final<<<1, 256, 0, stream>>>(gates_ws, cn, pitch_W, pitch_b,
                                  dur_W, dur_b, etrue_ws, out);
}

// Round 2
// 52.971 us; speedup vs baseline: 2.5537x; 2.5537x over previous
//
#include <hip/hip_runtime.h>
#include <hip/hip_bf16.h>
#include <math.h>

#define H 256
#define L_SEQ 131072
#define IN_DIM 50
#define NBLK2 64

__device__ __forceinline__ float wave_reduce_sum(float v) {
#pragma unroll
  for (int off = 32; off > 0; off >>= 1) v += __shfl_xor(v, off, 64);
  return v;
}

// ---------------- K1: one-pass online-softmax attention, per-block partials ----
__global__ __launch_bounds__(256) void k1_attn_partial(
    const float* __restrict__ E, const float* __restrict__ h,
    float* __restrict__ part, int rows_per_block) {
  const int b = blockIdx.x;
  const int w = threadIdx.x >> 6;
  const int lane = threadIdx.x & 63;
  const float4 hreg = reinterpret_cast<const float4*>(h)[lane];
  float m = -3.0e38f, s = 0.f;
  float4 acc = make_float4(0.f, 0.f, 0.f, 0.f);
  const int base = b * rows_per_block;
  for (int r = w; r < rows_per_block; r += 4) {
    const float4 e = reinterpret_cast<const float4*>(E)[(size_t)(base + r) * 64 + lane];
    float d = e.x * hreg.x + e.y * hreg.y + e.z * hreg.z + e.w * hreg.w;
    d = wave_reduce_sum(d);              // score, uniform across wave
    if (d > m) {                         // wave-uniform branch
      const float sc = __expf(m - d);
      s = s * sc + 1.f;
      acc.x = acc.x * sc + e.x;
      acc.y = acc.y * sc + e.y;
      acc.z = acc.z * sc + e.z;
      acc.w = acc.w * sc + e.w;
      m = d;
    } else {
      const float wt = __expf(d - m);
      s += wt;
      acc.x += wt * e.x; acc.y += wt * e.y; acc.z += wt * e.z; acc.w += wt * e.w;
    }
  }
  __shared__ float sm[4], ss[4];
  __shared__ float sacc[4][H];
  sacc[w][4 * lane + 0] = acc.x;
  sacc[w][4 * lane + 1] = acc.y;
  sacc[w][4 * lane + 2] = acc.z;
  sacc[w][4 * lane + 3] = acc.w;
  if (lane == 0) { sm[w] = m; ss[w] = s; }
  __syncthreads();
  const int t = threadIdx.x;
  const float M = fmaxf(fmaxf(sm[0], sm[1]), fmaxf(sm[2], sm[3]));
  const float e0 = __expf(sm[0] - M), e1 = __expf(sm[1] - M);
  const float e2 = __expf(sm[2] - M), e3 = __expf(sm[3] - M);
  const float ctx = e0 * sacc[0][t] + e1 * sacc[1][t] + e2 * sacc[2][t] + e3 * sacc[3][t];
  float* pb = part + (size_t)b * 258;
  pb[2 + t] = ctx;
  if (t == 0) { pb[0] = M; pb[1] = e0 * ss[0] + e1 * ss[1] + e2 * ss[2] + e3 * ss[3]; }
}

// ---------------- K2a: merge `group` partials -> 1 partial (64 blocks) ----
__global__ __launch_bounds__(256) void k2a_merge(
    const float* __restrict__ part, float* __restrict__ part2, int group) {
  const int j = blockIdx.x;
  const int t = threadIdx.x;
  const int base = j * group;
  __shared__ float sm2[64], ss2[64];
  __shared__ float Msh;
  if (t < group) {
    sm2[t] = part[(size_t)(base + t) * 258];
    ss2[t] = part[(size_t)(base + t) * 258 + 1];
  }
  __syncthreads();
  if (t == 0) {
    float M = sm2[0];
    for (int i = 1; i < group; i++) M = fmaxf(M, sm2[i]);
    Msh = M;
  }
  __syncthreads();
  const float M = Msh;
  float lc = 0.f;
  for (int g = 0; g < group; g++)
    lc += __expf(sm2[g] - M) * part[(size_t)(base + g) * 258 + 2 + t];
  float* pb = part2 + (size_t)j * 258;
  pb[2 + t] = lc;
  if (t == 0) {
    float S = 0.f;
    for (int g = 0; g < group; g++) S += __expf(sm2[g] - M) * ss2[g];
    pb[0] = M; pb[1] = S;
  }
}

// ---------------- K2b: final combine -> ctx, attn proj, embeddings, x[50] ----
__global__ __launch_bounds__(256) void k2b_final_combine(
    const float* __restrict__ part2, int n2,
    const float* __restrict__ chord_emb, const float* __restrict__ pitch_emb,
    const float* __restrict__ dur_emb,
    const float* __restrict__ attn_W, const float* __restrict__ attn_b,
    const int* __restrict__ sec_p, const int* __restrict__ chord_p,
    const int* __restrict__ tp_p, const int* __restrict__ note_p,
    float* __restrict__ x_ws, float* __restrict__ etrue_ws) {
  const int t = threadIdx.x;
  __shared__ float sm2[64], ss2[64];
  __shared__ float Msh, Ssh;
  __shared__ float ctx_s[H];
  if (t < n2) {
    sm2[t] = part2[(size_t)t * 258];
    ss2[t] = part2[(size_t)t * 258 + 1];
  }
  __syncthreads();
  if (t == 0) {
    float M = sm2[0];
    for (int i = 1; i < n2; i++) M = fmaxf(M, sm2[i]);
    float S = 0.f;
    for (int i = 0; i < n2; i++) S += __expf(sm2[i] - M) * ss2[i];
    Msh = M; Ssh = S;
  }
  __syncthreads();
  const float M = Msh;
  const float Sinv = 1.f / Ssh;
  float lc = 0.f;
  for (int g = 0; g < n2; g++)
    lc += __expf(sm2[g] - M) * part2[(size_t)g * 258 + 2 + t];
  ctx_s[t] = lc * Sinv;
  __syncthreads();
  const int lane = t & 63, w = t >> 6;
  // ctx10 = attn_W @ ctx + attn_b (10 rows over 4 waves)
  for (int row = w; row < 10; row += 4) {
    const float4 c4 = reinterpret_cast<const float4*>(ctx_s)[lane];
    const float4 a4 = reinterpret_cast<const float4*>(attn_W + row * H)[lane];
    float d = c4.x * a4.x + c4.y * a4.y + c4.z * a4.z + c4.w * a4.w;
    d = wave_reduce_sum(d);
    if (lane == 0) x_ws[40 + row] = d + attn_b[row];
  }
  // embedding gathers: x = [e_pitch, e_dur, e_chord, e_sec, ctx10]
  if (t < 10)       x_ws[t] = pitch_emb[note_p[0] * 10 + t];
  else if (t < 20)  x_ws[t] = dur_emb[note_p[1] * 10 + (t - 10)];
  else if (t < 30)  x_ws[t] = chord_emb[chord_p[0] * 10 + (t - 20)];
  else if (t < 40)  x_ws[t] = chord_emb[sec_p[0] * 10 + (t - 30)];
  else if (t < 50)  etrue_ws[t - 40] = pitch_emb[tp_p[0] * 10 + (t - 40)];
}

// ---------------- K3: gates = W_ih@x + W_hh@h + b_ih + b_hh (256 blocks) ----
__global__ __launch_bounds__(256) void k3_gates(
    const float* __restrict__ W_ih, const float* __restrict__ W_hh,
    const float* __restrict__ b_ih, const float* __restrict__ b_hh,
    const float* __restrict__ h, const float* __restrict__ x_ws,
    float* __restrict__ gates_ws) {
  __shared__ float x_s[IN_DIM];
  const int t = threadIdx.x;
  if (t < IN_DIM) x_s[t] = x_ws[t];
  __syncthreads();
  const int lane = t & 63, w = t >> 6;
  const int row = blockIdx.x * 4 + w;
  const float4 hreg = reinterpret_cast<const float4*>(h)[lane];
  const float4 wv = reinterpret_cast<const float4*>(W_hh + (size_t)row * H)[lane];
  float d = wv.x * hreg.x + wv.y * hreg.y + wv.z * hreg.z + wv.w * hreg.w;
  if (lane < IN_DIM) d += W_ih[row * IN_DIM + lane] * x_s[lane];
  d = wave_reduce_sum(d);
  if (lane == 0) gates_ws[row] = d + b_ih[row] + b_hh[row];
}

// ---------------- K4: LSTM nonlinearity + both heads + outputs (8 blocks) ----
__global__ __launch_bounds__(256) void k4_final(
    const float* __restrict__ gates_ws, const float* __restrict__ c_in,
    const float* __restrict__ pitch_W, const float* __restrict__ pitch_b,
    const float* __restrict__ dur_W, const float* __restrict__ dur_b,
    const float* __restrict__ etrue_ws, float* __restrict__ out) {
  __shared__ float hs[H];
  __shared__ float et[16];
  const int t = threadIdx.x;
  const int b = blockIdx.x;
  {
    const float ig = gates_ws[t], fg = gates_ws[256 + t];
    const float gg = gates_ws[512 + t], og = gates_ws[768 + t];
    const float i_s = 1.f / (1.f + __expf(-ig));
    const float f_s = 1.f / (1.f + __expf(-fg));
    const float g_t = tanhf(gg);
    const float o_s = 1.f / (1.f + __expf(-og));
    const float cn = f_s * c_in[t] + i_s * g_t;
    const float hn = o_s * tanhf(cn);
    if (b == 0) {
      out[79 + t] = hn;        // h_new at [79, 335)
      out[335 + t] = cn;       // c_new at [335, 591)
    }
    hs[t] = hn;
  }
  if (t < 10) et[t] = etrue_ws[t];
  __syncthreads();
  const int lane = t & 63, w = t >> 6;
  const int gw = b * 4 + w;    // 32 global waves
  const float4 h4 = reinterpret_cast<const float4*>(hs)[lane];
  // pitch head: 63 rows across 32 waves
  for (int row = gw; row < 63; row += 32) {
    const float4 pw = reinterpret_cast<const float4*>(pitch_W + (size_t)row * H)[lane];
    float d = pw.x * h4.x + pw.y * h4.y + pw.z * h4.z + pw.w * h4.w;
    d = wave_reduce_sum(d);
    if (lane == 0) out[row] = d + pitch_b[row];
  }
  // dur head: 16 rows over concat([e_true, h_new]) (266)
  for (int row = gw; row < 16; row += 32) {
    const float* dw = dur_W + (size_t)row * 266;
    float d = 0.f;
    for (int k = lane; k < 266; k += 64)
      d += dw[k] * (k < 10 ? et[k] : hs[k - 10]);
    d = wave_reduce_sum(d);
    if (lane == 0) out[63 + row] = d + dur_b[row];
  }
}

extern "C" void kernel_launch(void* const* d_in, const int* in_sizes, int n_in,
                              void* d_out, int out_size, void* d_ws, size_t ws_size,
                              hipStream_t stream) {
  const int* sec       = (const int*)d_in[0];
  const int* chord     = (const int*)d_in[1];
  const int* tp        = (const int*)d_in[2];
  const int* note      = (const int*)d_in[3];
  const float* hn      = (const float*)d_in[4];
  const float* cn      = (const float*)d_in[5];
  const float* E       = (const float*)d_in[6];
  const float* chord_e = (const float*)d_in[7];
  const float* pitch_e = (const float*)d_in[8];
  const float* dur_e   = (const float*)d_in[9];
  const float* W_ih    = (const float*)d_in[10];
  const float* W_hh    = (const float*)d_in[11];
  const float* b_ih    = (const float*)d_in[12];
  const float* b_hh    = (const float*)d_in[13];
  const float* pitch_W = (const float*)d_in[14];
  const float* pitch_b = (const float*)d_in[15];
  const float* dur_W   = (const float*)d_in[16];
  const float* dur_b   = (const float*)d_in[17];
  const float* attn_W  = (const float*)d_in[18];
  const float* attn_b  = (const float*)d_in[19];
  float* out = (float*)d_out;
  float* ws = (float*)d_ws;

  // pick K1 block count (power of two so rows divide evenly), bounded by ws
  int nblk = 1024;
  while (nblk > NBLK2 &&
         (size_t)(nblk * 258 + NBLK2 * 258 + 2048) * sizeof(float) > ws_size)
    nblk >>= 1;
  const int rpb = L_SEQ / nblk;
  const int group = nblk / NBLK2;

  float* part  = ws;                                // nblk * 258
  float* part2 = ws + (size_t)nblk * 258;           // 64 * 258
  float* x_ws  = part2 + (size_t)NBLK2 * 258;       // 50 (+pad)
  float* etrue_ws = x_ws + 64;                      // 10
  float* gates_ws = x_ws + 128;                     // 1024

  k1_attn_partial<<<nblk, 256, 0, stream>>>(E, hn, part, rpb);
  k2a_merge<<<NBLK2, 256, 0, stream>>>(part, part2, group);
  k2b_final_combine<<<1, 256, 0, stream>>>(part2, NBLK2, chord_e, pitch_e, dur_e,
                                           attn_W, attn_b, sec, chord, tp, note,
                                           x_ws, etrue_ws);
  k3_gates<<<256, 256, 0, stream>>>(W_ih, W_hh, b_ih, b_hh, hn, x_ws, gates_ws);
  k4_final<<<8, 256, 0, stream>>>(gates_ws, cn, pitch_W, pitch_b,
                                  dur_W, dur_b, etrue_ws, out);
}

// Round 3
// 39.453 us; speedup vs baseline: 3.4287x; 1.3426x over previous
//
#include <hip/hip_runtime.h>
#include <hip/hip_bf16.h>
#include <math.h>

#define H 256
#define L_SEQ 131072
#define IN_DIM 50
#define NBLK 1024           // attention blocks
#define RPB (L_SEQ / NBLK)  // 128 rows per block

__device__ __forceinline__ float wave_reduce_sum(float v) {
#pragma unroll
  for (int off = 32; off > 0; off >>= 1) v += __shfl_xor(v, off, 64);
  return v;
}

// ---- K1: blocks [0,NBLK): softmax-sum partials (M=0) + attn_W projection.
//          blocks [NBLK,NBLK+256): ghh = W_hh@h + b_ih + b_hh.
__global__ __launch_bounds__(256) void k1_attn(
    const float* __restrict__ E, const float* __restrict__ h,
    const float* __restrict__ attn_W,
    const float* __restrict__ W_hh, const float* __restrict__ b_ih,
    const float* __restrict__ b_hh,
    float* __restrict__ p10,   // [11][NBLK] column-major partials
    float* __restrict__ ghh) { // [1024]
  const int b = blockIdx.x;
  const int lane = threadIdx.x & 63;
  const int w = threadIdx.x >> 6;
  const float4 hreg = reinterpret_cast<const float4*>(h)[lane];

  if (b >= NBLK) {  // ---- gate-row blocks (overlap the E scan) ----
    const int row = (b - NBLK) * 4 + w;
    const float4 wv = reinterpret_cast<const float4*>(W_hh + (size_t)row * H)[lane];
    float d = wv.x * hreg.x + wv.y * hreg.y + wv.z * hreg.z + wv.w * hreg.w;
    d = wave_reduce_sum(d);
    if (lane == 0) ghh[row] = d + b_ih[row] + b_hh[row];
    return;
  }

  // ---- attention chunk: fixed M=0 online sum ----
  float s = 0.f;
  float4 acc = make_float4(0.f, 0.f, 0.f, 0.f);
  const float4* E4 = reinterpret_cast<const float4*>(E);
  const int base = b * RPB;
#pragma unroll 2
  for (int r = w; r < RPB; r += 8) {
    const float4 e0 = E4[(size_t)(base + r) * 64 + lane];
    const float4 e1 = E4[(size_t)(base + r + 4) * 64 + lane];
    float d0 = e0.x * hreg.x + e0.y * hreg.y + e0.z * hreg.z + e0.w * hreg.w;
    float d1 = e1.x * hreg.x + e1.y * hreg.y + e1.z * hreg.z + e1.w * hreg.w;
#pragma unroll
    for (int off = 32; off > 0; off >>= 1) {
      d0 += __shfl_xor(d0, off, 64);
      d1 += __shfl_xor(d1, off, 64);
    }
    const float w0 = __expf(d0), w1 = __expf(d1);
    s += w0 + w1;
    acc.x += w0 * e0.x + w1 * e1.x;
    acc.y += w0 * e0.y + w1 * e1.y;
    acc.z += w0 * e0.z + w1 * e1.z;
    acc.w += w0 * e0.w + w1 * e1.w;
  }
  __shared__ float ss[4];
  __shared__ float sacc[4][H];
  sacc[w][4 * lane + 0] = acc.x;
  sacc[w][4 * lane + 1] = acc.y;
  sacc[w][4 * lane + 2] = acc.z;
  sacc[w][4 * lane + 3] = acc.w;
  if (lane == 0) ss[w] = s;
  __syncthreads();
  const int t = threadIdx.x;
  __shared__ float ctx_s[H];
  ctx_s[t] = sacc[0][t] + sacc[1][t] + sacc[2][t] + sacc[3][t];
  __syncthreads();
  // p10[r] = attn_W[r] @ ctx_s  (rows 0..9 over 4 waves), p10[10] = s
  const float4 c4 = reinterpret_cast<const float4*>(ctx_s)[lane];
  for (int row = w; row < 10; row += 4) {
    const float4 a4 = reinterpret_cast<const float4*>(attn_W + row * H)[lane];
    float d = c4.x * a4.x + c4.y * a4.y + c4.z * a4.z + c4.w * a4.w;
    d = wave_reduce_sum(d);
    if (lane == 0) p10[row * NBLK + b] = d;
  }
  if (t == 0) p10[10 * NBLK + b] = ss[0] + ss[1] + ss[2] + ss[3];
}

// ---- K2: reduce 11 x NBLK partials -> ctx10, assemble x[50], etrue ----
__global__ __launch_bounds__(1024) void k2_combine(
    const float* __restrict__ p10,
    const float* __restrict__ chord_emb, const float* __restrict__ pitch_emb,
    const float* __restrict__ dur_emb, const float* __restrict__ attn_b,
    const int* __restrict__ sec_p, const int* __restrict__ chord_p,
    const int* __restrict__ tp_p, const int* __restrict__ note_p,
    float* __restrict__ x_ws, float* __restrict__ etrue_ws) {
  const int t = threadIdx.x;
  const int lane = t & 63, w = t >> 6;  // 16 waves
  __shared__ float red[11];
  if (w < 11) {  // wave w reduces column w
    float v = 0.f;
#pragma unroll
    for (int i = 0; i < NBLK / 64; i++) v += p10[w * NBLK + lane + 64 * i];
    v = wave_reduce_sum(v);
    if (lane == 0) red[w] = v;
  }
  __syncthreads();
  const float Sinv = 1.f / red[10];
  if (t < 10)       x_ws[40 + t] = red[t] * Sinv + attn_b[t];
  else if (t < 20)  x_ws[t - 10] = pitch_emb[note_p[0] * 10 + (t - 10)];
  else if (t < 30)  x_ws[t - 20 + 10] = dur_emb[note_p[1] * 10 + (t - 20)];
  else if (t < 40)  x_ws[t - 30 + 20] = chord_emb[chord_p[0] * 10 + (t - 30)];
  else if (t < 50)  x_ws[t - 40 + 30] = chord_emb[sec_p[0] * 10 + (t - 40)];
  else if (t < 60)  etrue_ws[t - 50] = pitch_emb[tp_p[0] * 10 + (t - 50)];
}

// ---- K3: gates = ghh + W_ih@x  (256 blocks, wave per row) ----
__global__ __launch_bounds__(256) void k3_gates(
    const float* __restrict__ W_ih, const float* __restrict__ ghh,
    const float* __restrict__ x_ws, float* __restrict__ gates_ws) {
  __shared__ float x_s[IN_DIM];
  const int t = threadIdx.x;
  if (t < IN_DIM) x_s[t] = x_ws[t];
  __syncthreads();
  const int lane = t & 63, w = t >> 6;
  const int row = blockIdx.x * 4 + w;
  float d = (lane < IN_DIM) ? W_ih[row * IN_DIM + lane] * x_s[lane] : 0.f;
  d = wave_reduce_sum(d);
  if (lane == 0) gates_ws[row] = d + ghh[row];
}

// ---- K4: LSTM nonlinearity + both heads + outputs (8 blocks) ----
__global__ __launch_bounds__(256) void k4_final(
    const float* __restrict__ gates_ws, const float* __restrict__ c_in,
    const float* __restrict__ pitch_W, const float* __restrict__ pitch_b,
    const float* __restrict__ dur_W, const float* __restrict__ dur_b,
    const float* __restrict__ etrue_ws, float* __restrict__ out) {
  __shared__ float hs[H];
  __shared__ float et[16];
  const int t = threadIdx.x;
  const int b = blockIdx.x;
  {
    const float ig = gates_ws[t], fg = gates_ws[256 + t];
    const float gg = gates_ws[512 + t], og = gates_ws[768 + t];
    const float i_s = 1.f / (1.f + __expf(-ig));
    const float f_s = 1.f / (1.f + __expf(-fg));
    const float g_t = tanhf(gg);
    const float o_s = 1.f / (1.f + __expf(-og));
    const float cn = f_s * c_in[t] + i_s * g_t;
    const float hn = o_s * tanhf(cn);
    if (b == 0) {
      out[79 + t] = hn;        // h_new at [79, 335)
      out[335 + t] = cn;       // c_new at [335, 591)
    }
    hs[t] = hn;
  }
  if (t < 10) et[t] = etrue_ws[t];
  __syncthreads();
  const int lane = t & 63, w = t >> 6;
  const int gw = b * 4 + w;    // 32 global waves
  const float4 h4 = reinterpret_cast<const float4*>(hs)[lane];
  for (int row = gw; row < 63; row += 32) {
    const float4 pw = reinterpret_cast<const float4*>(pitch_W + (size_t)row * H)[lane];
    float d = pw.x * h4.x + pw.y * h4.y + pw.z * h4.z + pw.w * h4.w;
    d = wave_reduce_sum(d);
    if (lane == 0) out[row] = d + pitch_b[row];
  }
  for (int row = gw; row < 16; row += 32) {
    const float* dw = dur_W + (size_t)row * 266;
    float d = 0.f;
    for (int k = lane; k < 266; k += 64)
      d += dw[k] * (k < 10 ? et[k] : hs[k - 10]);
    d = wave_reduce_sum(d);
    if (lane == 0) out[63 + row] = d + dur_b[row];
  }
}

extern "C" void kernel_launch(void* const* d_in, const int* in_sizes, int n_in,
                              void* d_out, int out_size, void* d_ws, size_t ws_size,
                              hipStream_t stream) {
  const int* sec       = (const int*)d_in[0];
  const int* chord     = (const int*)d_in[1];
  const int* tp        = (const int*)d_in[2];
  const int* note      = (const int*)d_in[3];
  const float* hn      = (const float*)d_in[4];
  const float* cn      = (const float*)d_in[5];
  const float* E       = (const float*)d_in[6];
  const float* chord_e = (const float*)d_in[7];
  const float* pitch_e = (const float*)d_in[8];
  const float* dur_e   = (const float*)d_in[9];
  const float* W_ih    = (const float*)d_in[10];
  const float* W_hh    = (const float*)d_in[11];
  const float* b_ih    = (const float*)d_in[12];
  const float* b_hh    = (const float*)d_in[13];
  const float* pitch_W = (const float*)d_in[14];
  const float* pitch_b = (const float*)d_in[15];
  const float* dur_W   = (const float*)d_in[16];
  const float* dur_b   = (const float*)d_in[17];
  const float* attn_W  = (const float*)d_in[18];
  const float* attn_b  = (const float*)d_in[19];
  float* out = (float*)d_out;
  float* ws = (float*)d_ws;

  float* p10      = ws;              // 11 * NBLK
  float* ghh      = ws + 11 * NBLK;  // 1024
  float* x_ws     = ghh + 1024;      // 50 (+pad)
  float* etrue_ws = x_ws + 64;       // 10 (+pad)
  float* gates_ws = x_ws + 128;      // 1024

  k1_attn<<<NBLK + 256, 256, 0, stream>>>(E, hn, attn_W, W_hh, b_ih, b_hh,
                                          p10, ghh);
  k2_combine<<<1, 1024, 0, stream>>>(p10, chord_e, pitch_e, dur_e, attn_b,
                                     sec, chord, tp, note, x_ws, etrue_ws);
  k3_gates<<<256, 256, 0, stream>>>(W_ih, ghh, x_ws, gates_ws);
  k4_final<<<8, 256, 0, stream>>>(gates_ws, cn, pitch_W, pitch_b,
                                  dur_W, dur_b, etrue_ws, out);
}

// Round 4
// 32.601 us; speedup vs baseline: 4.1493x; 1.2102x over previous
//
#include <hip/hip_runtime.h>
#include <hip/hip_bf16.h>
#include <math.h>

#define H 256
#define L_SEQ 131072
#define NBLK 1024           // attention blocks
#define RPB (L_SEQ / NBLK)  // 128 rows per block

__device__ __forceinline__ float wave_reduce_sum(float v) {
#pragma unroll
  for (int off = 32; off > 0; off >>= 1) v += __shfl_xor(v, off, 64);
  return v;
}

// ---- K1: 1024 blocks. All: softmax-sum partial (M=0) + attn_W projection.
//      blocks 0..255 also: ghh2 = W_hh@h + b_ih + b_hh + W_ih[:,0:40]@emb,
//                          and transpose W_ih[:,40:50] -> WcT.
//      blocks 256..271 also: warm L3 with head weights.
__global__ __launch_bounds__(256) void k1_attn(
    const float* __restrict__ E, const float* __restrict__ h,
    const float* __restrict__ attn_W, const float* __restrict__ W_hh,
    const float* __restrict__ b_ih, const float* __restrict__ b_hh,
    const float* __restrict__ W_ih,
    const float* __restrict__ chord_emb, const float* __restrict__ pitch_emb,
    const float* __restrict__ dur_emb,
    const int* __restrict__ sec_p, const int* __restrict__ chord_p,
    const int* __restrict__ note_p,
    const float* __restrict__ pitch_W, const float* __restrict__ dur_W,
    float* __restrict__ p10, float* __restrict__ ghh2,
    float* __restrict__ WcT, float* __restrict__ dummy) {
  const int b = blockIdx.x;
  const int t = threadIdx.x;
  const int lane = t & 63;
  const int w = t >> 6;
  const float4 hreg = reinterpret_cast<const float4*>(h)[lane];

  // ---- side work (rides along with the E scan) ----
  if (b < 256) {
    const int r = b * 4 + w;  // gate row
    const float4 wv = reinterpret_cast<const float4*>(W_hh + (size_t)r * H)[lane];
    float d = wv.x * hreg.x + wv.y * hreg.y + wv.z * hreg.z + wv.w * hreg.w;
    if (lane < 50) {
      const float wih = W_ih[r * 50 + lane];
      if (lane < 40) {
        int idx; const float* tbl;
        if (lane < 10)      { tbl = pitch_emb; idx = note_p[0] * 10 + lane; }
        else if (lane < 20) { tbl = dur_emb;   idx = note_p[1] * 10 + lane - 10; }
        else if (lane < 30) { tbl = chord_emb; idx = chord_p[0] * 10 + lane - 20; }
        else                { tbl = chord_emb; idx = sec_p[0] * 10 + lane - 30; }
        d += wih * tbl[idx];
      } else {
        WcT[(lane - 40) * NBLK + r] = wih;  // transpose cols 40..49
      }
    }
    d = wave_reduce_sum(d);
    if (lane == 0) ghh2[r] = d + b_ih[r] + b_hh[r];
  } else if (b < 272) {
    const int slice = b - 256;  // warm L3 for the tail
    float a = 0.f;
    const float4* pw4 = reinterpret_cast<const float4*>(pitch_W);
    for (int i = slice * 256 + t; i < 4032; i += 16 * 256) {
      float4 v = pw4[i]; a += v.x + v.y + v.z + v.w;
    }
    const float4* dw4 = reinterpret_cast<const float4*>(dur_W);
    for (int i = slice * 256 + t; i < 1064; i += 16 * 256) {
      float4 v = dw4[i]; a += v.x + v.y + v.z + v.w;
    }
    a = wave_reduce_sum(a);
    if (lane == 0) dummy[slice * 4 + w] = a;
  }

  // ---- attention chunk: fixed M=0 exp-sum, 4-row unroll ----
  float s = 0.f;
  float4 acc = make_float4(0.f, 0.f, 0.f, 0.f);
  const float4* E4 = reinterpret_cast<const float4*>(E);
  const size_t base = (size_t)b * RPB;
  for (int r = w; r < RPB; r += 16) {
    const float4 e0 = E4[(base + r) * 64 + lane];
    const float4 e1 = E4[(base + r + 4) * 64 + lane];
    const float4 e2 = E4[(base + r + 8) * 64 + lane];
    const float4 e3 = E4[(base + r + 12) * 64 + lane];
    float d0 = e0.x * hreg.x + e0.y * hreg.y + e0.z * hreg.z + e0.w * hreg.w;
    float d1 = e1.x * hreg.x + e1.y * hreg.y + e1.z * hreg.z + e1.w * hreg.w;
    float d2 = e2.x * hreg.x + e2.y * hreg.y + e2.z * hreg.z + e2.w * hreg.w;
    float d3 = e3.x * hreg.x + e3.y * hreg.y + e3.z * hreg.z + e3.w * hreg.w;
#pragma unroll
    for (int off = 32; off > 0; off >>= 1) {
      d0 += __shfl_xor(d0, off, 64);
      d1 += __shfl_xor(d1, off, 64);
      d2 += __shfl_xor(d2, off, 64);
      d3 += __shfl_xor(d3, off, 64);
    }
    const float w0 = __expf(d0), w1 = __expf(d1);
    const float w2 = __expf(d2), w3 = __expf(d3);
    s += (w0 + w1) + (w2 + w3);
    acc.x += w0 * e0.x + w1 * e1.x + w2 * e2.x + w3 * e3.x;
    acc.y += w0 * e0.y + w1 * e1.y + w2 * e2.y + w3 * e3.y;
    acc.z += w0 * e0.z + w1 * e1.z + w2 * e2.z + w3 * e3.z;
    acc.w += w0 * e0.w + w1 * e1.w + w2 * e2.w + w3 * e3.w;
  }
  __shared__ float ss[4];
  __shared__ float sacc[4][H];
  sacc[w][4 * lane + 0] = acc.x;
  sacc[w][4 * lane + 1] = acc.y;
  sacc[w][4 * lane + 2] = acc.z;
  sacc[w][4 * lane + 3] = acc.w;
  if (lane == 0) ss[w] = s;
  __syncthreads();
  __shared__ float ctx_s[H];
  ctx_s[t] = sacc[0][t] + sacc[1][t] + sacc[2][t] + sacc[3][t];
  __syncthreads();
  const float4 c4 = reinterpret_cast<const float4*>(ctx_s)[lane];
  for (int row = w; row < 10; row += 4) {
    const float4 a4 = reinterpret_cast<const float4*>(attn_W + row * H)[lane];
    float d = c4.x * a4.x + c4.y * a4.y + c4.z * a4.z + c4.w * a4.w;
    d = wave_reduce_sum(d);
    if (lane == 0) p10[row * NBLK + b] = d;
  }
  if (t == 0) p10[10 * NBLK + b] = (ss[0] + ss[1]) + (ss[2] + ss[3]);
}

// ---- K2: fused tail, 4 blocks x 1024 thr. Each block redundantly:
//      combine p10 -> ctx10 -> gates -> LSTM; then waves split the head rows.
__global__ __launch_bounds__(1024) void k2_tail(
    const float* __restrict__ p10, const float* __restrict__ ghh2,
    const float* __restrict__ WcT, const float* __restrict__ attn_b,
    const float* __restrict__ c_in,
    const float* __restrict__ pitch_W, const float* __restrict__ pitch_b,
    const float* __restrict__ dur_W, const float* __restrict__ dur_b,
    const float* __restrict__ pitch_emb, const int* __restrict__ tp_p,
    float* __restrict__ out) {
  const int t = threadIdx.x;
  const int lane = t & 63, w = t >> 6;  // 16 waves
  __shared__ float red[11];
  __shared__ float ctxsh[10];
  __shared__ float gsh[1024];
  __shared__ float hsh[H];
  __shared__ float etsh[10];
  if (w < 11) {  // wave w reduces partial column w (1024 values, float4)
    const float4* pc = reinterpret_cast<const float4*>(p10 + w * NBLK);
    const float4 a0 = pc[lane], a1 = pc[lane + 64];
    const float4 a2 = pc[lane + 128], a3 = pc[lane + 192];
    float v = (a0.x + a0.y + a0.z + a0.w) + (a1.x + a1.y + a1.z + a1.w) +
              (a2.x + a2.y + a2.z + a2.w) + (a3.x + a3.y + a3.z + a3.w);
    v = wave_reduce_sum(v);
    if (lane == 0) red[w] = v;
  }
  if (t >= 704 && t < 714) etsh[t - 704] = pitch_emb[tp_p[0] * 10 + (t - 704)];
  __syncthreads();
  if (t < 10) ctxsh[t] = red[t] / red[10] + attn_b[t];
  __syncthreads();
  float g = ghh2[t];
#pragma unroll
  for (int c = 0; c < 10; c++) g += WcT[c * NBLK + t] * ctxsh[c];
  gsh[t] = g;
  __syncthreads();
  if (t < H) {
    const float i_s = 1.f / (1.f + __expf(-gsh[t]));
    const float f_s = 1.f / (1.f + __expf(-gsh[256 + t]));
    const float g_t = tanhf(gsh[512 + t]);
    const float o_s = 1.f / (1.f + __expf(-gsh[768 + t]));
    const float cn = f_s * c_in[t] + i_s * g_t;
    const float hn = o_s * tanhf(cn);
    if (blockIdx.x == 0) {
      out[79 + t] = hn;   // h_new at [79, 335)
      out[335 + t] = cn;  // c_new at [335, 591)
    }
    hsh[t] = hn;
  }
  __syncthreads();
  const int gw = blockIdx.x * 16 + w;  // 64 global waves
  const float4 h4 = reinterpret_cast<const float4*>(hsh)[lane];
  if (gw < 63) {  // pitch head rows
    const float4 pw = reinterpret_cast<const float4*>(pitch_W + (size_t)gw * H)[lane];
    float d = pw.x * h4.x + pw.y * h4.y + pw.z * h4.z + pw.w * h4.w;
    d = wave_reduce_sum(d);
    if (lane == 0) out[gw] = d + pitch_b[gw];
  }
  if (gw >= 48) {  // dur head rows 0..15 (block 3)
    const int row = gw - 48;
    const float* dw = dur_W + (size_t)row * 266;
    float d = 0.f;
    for (int k = lane; k < 266; k += 64)
      d += dw[k] * (k < 10 ? etsh[k] : hsh[k - 10]);
    d = wave_reduce_sum(d);
    if (lane == 0) out[63 + row] = d + dur_b[row];
  }
}

extern "C" void kernel_launch(void* const* d_in, const int* in_sizes, int n_in,
                              void* d_out, int out_size, void* d_ws, size_t ws_size,
                              hipStream_t stream) {
  const int* sec       = (const int*)d_in[0];
  const int* chord     = (const int*)d_in[1];
  const int* tp        = (const int*)d_in[2];
  const int* note      = (const int*)d_in[3];
  const float* hn      = (const float*)d_in[4];
  const float* cn      = (const float*)d_in[5];
  const float* E       = (const float*)d_in[6];
  const float* chord_e = (const float*)d_in[7];
  const float* pitch_e = (const float*)d_in[8];
  const float* dur_e   = (const float*)d_in[9];
  const float* W_ih    = (const float*)d_in[10];
  const float* W_hh    = (const float*)d_in[11];
  const float* b_ih    = (const float*)d_in[12];
  const float* b_hh    = (const float*)d_in[13];
  const float* pitch_W = (const float*)d_in[14];
  const float* pitch_b = (const float*)d_in[15];
  const float* dur_W   = (const float*)d_in[16];
  const float* dur_b   = (const float*)d_in[17];
  const float* attn_W  = (const float*)d_in[18];
  const float* attn_b  = (const float*)d_in[19];
  float* out = (float*)d_out;
  float* ws = (float*)d_ws;

  float* p10   = ws;                 // 11 * 1024
  float* ghh2  = ws + 11 * NBLK;     // 1024
  float* WcT   = ghh2 + 1024;        // 10 * 1024
  float* dummy = WcT + 10 * NBLK;    // 64

  k1_attn<<<NBLK, 256, 0, stream>>>(E, hn, attn_W, W_hh, b_ih, b_hh, W_ih,
                                    chord_e, pitch_e, dur_e, sec, chord, note,
                                    pitch_W, dur_W, p10, ghh2, WcT, dummy);
  k2_tail<<<4, 1024, 0, stream>>>(p10, ghh2, WcT, attn_b, cn,
                                  pitch_W, pitch_b, dur_W, dur_b,
                                  pitch_e, tp, out);
}

// Round 5
// 32.123 us; speedup vs baseline: 4.2111x; 1.0149x over previous
//
#include <hip/hip_runtime.h>
#include <hip/hip_bf16.h>
#include <math.h>

#define H 256
#define L_SEQ 131072
#define NBLK 1024           // attention blocks
#define RPB (L_SEQ / NBLK)  // 128 rows per block

__device__ __forceinline__ float wave_reduce_sum(float v) {
#pragma unroll
  for (int off = 32; off > 0; off >>= 1) v += __shfl_xor(v, off, 64);
  return v;
}

// ---- K1: 1024 blocks. All: softmax-sum partial (M=0) + attn_W projection.
//      blocks 0..255 also (post-scan): ghh2 = W_hh@h + b + W_ih[:,0:40]@emb,
//                                      transpose W_ih[:,40:50] -> WcT.
//      blocks 256..271 also: warm L3 with head weights.
__global__ __launch_bounds__(256, 4) void k1_attn(
    const float* __restrict__ E, const float* __restrict__ h,
    const float* __restrict__ attn_W, const float* __restrict__ W_hh,
    const float* __restrict__ b_ih, const float* __restrict__ b_hh,
    const float* __restrict__ W_ih,
    const float* __restrict__ chord_emb, const float* __restrict__ pitch_emb,
    const float* __restrict__ dur_emb,
    const int* __restrict__ sec_p, const int* __restrict__ chord_p,
    const int* __restrict__ note_p,
    const float* __restrict__ pitch_W, const float* __restrict__ dur_W,
    float* __restrict__ p10, float* __restrict__ ghh2,
    float* __restrict__ WcT, float* __restrict__ dummy) {
  const int b = blockIdx.x;
  const int t = threadIdx.x;
  const int lane = t & 63;
  const int w = t >> 6;
  const float4 hreg = reinterpret_cast<const float4*>(h)[lane];

  // ---- attention chunk: fixed M=0 exp-sum, 8-row unroll (8 KB in flight/wave)
  float s = 0.f;
  float4 acc = make_float4(0.f, 0.f, 0.f, 0.f);
  const float4* E4 = reinterpret_cast<const float4*>(E);
  const size_t base = (size_t)b * RPB;
#pragma unroll
  for (int k = 0; k < RPB / 32; ++k) {
    const int r = w * 8 + 32 * k;
    float4 e[8];
#pragma unroll
    for (int j = 0; j < 8; ++j) e[j] = E4[(base + r + j) * 64 + lane];
    float d[8];
#pragma unroll
    for (int j = 0; j < 8; ++j)
      d[j] = e[j].x * hreg.x + e[j].y * hreg.y + e[j].z * hreg.z + e[j].w * hreg.w;
#pragma unroll
    for (int off = 32; off > 0; off >>= 1) {
#pragma unroll
      for (int j = 0; j < 8; ++j) d[j] += __shfl_xor(d[j], off, 64);
    }
#pragma unroll
    for (int j = 0; j < 8; ++j) {
      const float wj = __expf(d[j]);
      s += wj;
      acc.x += wj * e[j].x;
      acc.y += wj * e[j].y;
      acc.z += wj * e[j].z;
      acc.w += wj * e[j].w;
    }
  }
  __shared__ float ss[4];
  __shared__ float4 sacc4[4][64];
  sacc4[w][lane] = acc;
  if (lane == 0) ss[w] = s;
  __syncthreads();
  __shared__ float ctx_s[H];
  {
    const float* sf = reinterpret_cast<const float*>(sacc4);
    ctx_s[t] = (sf[t] + sf[256 + t]) + (sf[512 + t] + sf[768 + t]);
  }
  __syncthreads();
  const float4 c4 = reinterpret_cast<const float4*>(ctx_s)[lane];
  for (int row = w; row < 10; row += 4) {
    const float4 a4 = reinterpret_cast<const float4*>(attn_W + row * H)[lane];
    float d = c4.x * a4.x + c4.y * a4.y + c4.z * a4.z + c4.w * a4.w;
    d = wave_reduce_sum(d);
    if (lane == 0) p10[row * NBLK + b] = d;
  }
  if (t == 0) p10[10 * NBLK + b] = (ss[0] + ss[1]) + (ss[2] + ss[3]);

  // ---- side work (hides in the drain phase) ----
  if (b < 256) {
    const int r = b * 4 + w;  // gate row
    const float4 wv = reinterpret_cast<const float4*>(W_hh + (size_t)r * H)[lane];
    float d = wv.x * hreg.x + wv.y * hreg.y + wv.z * hreg.z + wv.w * hreg.w;
    if (lane < 50) {
      const float wih = W_ih[r * 50 + lane];
      if (lane < 40) {
        int idx; const float* tbl;
        if (lane < 10)      { tbl = pitch_emb; idx = note_p[0] * 10 + lane; }
        else if (lane < 20) { tbl = dur_emb;   idx = note_p[1] * 10 + lane - 10; }
        else if (lane < 30) { tbl = chord_emb; idx = chord_p[0] * 10 + lane - 20; }
        else                { tbl = chord_emb; idx = sec_p[0] * 10 + lane - 30; }
        d += wih * tbl[idx];
      } else {
        WcT[(lane - 40) * NBLK + r] = wih;  // transpose cols 40..49
      }
    }
    d = wave_reduce_sum(d);
    if (lane == 0) ghh2[r] = d + b_ih[r] + b_hh[r];
  } else if (b < 272) {
    const int slice = b - 256;  // warm L3 for the tail
    float a = 0.f;
    const float4* pw4 = reinterpret_cast<const float4*>(pitch_W);
    for (int i = slice * 256 + t; i < 4032; i += 16 * 256) {
      float4 v = pw4[i]; a += v.x + v.y + v.z + v.w;
    }
    const float4* dw4 = reinterpret_cast<const float4*>(dur_W);
    for (int i = slice * 256 + t; i < 1064; i += 16 * 256) {
      float4 v = dw4[i]; a += v.x + v.y + v.z + v.w;
    }
    a = wave_reduce_sum(a);
    if (lane == 0) dummy[slice * 4 + w] = a;
  }
}

// ---- K2: fused tail, 4 blocks x 1024 thr. Each block redundantly:
//      combine p10 -> ctx10 -> gates -> LSTM; then waves split the head rows.
__global__ __launch_bounds__(1024) void k2_tail(
    const float* __restrict__ p10, const float* __restrict__ ghh2,
    const float* __restrict__ WcT, const float* __restrict__ attn_b,
    const float* __restrict__ c_in,
    const float* __restrict__ pitch_W, const float* __restrict__ pitch_b,
    const float* __restrict__ dur_W, const float* __restrict__ dur_b,
    const float* __restrict__ pitch_emb, const int* __restrict__ tp_p,
    float* __restrict__ out) {
  const int t = threadIdx.x;
  const int lane = t & 63, w = t >> 6;  // 16 waves
  __shared__ float red[11];
  __shared__ float ctxsh[10];
  __shared__ float gsh[1024];
  __shared__ float hsh[H];
  __shared__ float etsh[10];
  if (w < 11) {  // wave w reduces partial column w (1024 values, float4)
    const float4* pc = reinterpret_cast<const float4*>(p10 + w * NBLK);
    const float4 a0 = pc[lane], a1 = pc[lane + 64];
    const float4 a2 = pc[lane + 128], a3 = pc[lane + 192];
    float v = (a0.x + a0.y + a0.z + a0.w) + (a1.x + a1.y + a1.z + a1.w) +
              (a2.x + a2.y + a2.z + a2.w) + (a3.x + a3.y + a3.z + a3.w);
    v = wave_reduce_sum(v);
    if (lane == 0) red[w] = v;
  }
  if (t >= 704 && t < 714) etsh[t - 704] = pitch_emb[tp_p[0] * 10 + (t - 704)];
  __syncthreads();
  if (t < 10) ctxsh[t] = red[t] / red[10] + attn_b[t];
  __syncthreads();
  float g = ghh2[t];
#pragma unroll
  for (int c = 0; c < 10; c++) g += WcT[c * NBLK + t] * ctxsh[c];
  gsh[t] = g;
  __syncthreads();
  if (t < H) {
    const float i_s = 1.f / (1.f + __expf(-gsh[t]));
    const float f_s = 1.f / (1.f + __expf(-gsh[256 + t]));
    const float g_t = tanhf(gsh[512 + t]);
    const float o_s = 1.f / (1.f + __expf(-gsh[768 + t]));
    const float cn = f_s * c_in[t] + i_s * g_t;
    const float hn = o_s * tanhf(cn);
    if (blockIdx.x == 0) {
      out[79 + t] = hn;   // h_new at [79, 335)
      out[335 + t] = cn;  // c_new at [335, 591)
    }
    hsh[t] = hn;
  }
  __syncthreads();
  const int gw = blockIdx.x * 16 + w;  // 64 global waves
  const float4 h4 = reinterpret_cast<const float4*>(hsh)[lane];
  if (gw < 63) {  // pitch head rows
    const float4 pw = reinterpret_cast<const float4*>(pitch_W + (size_t)gw * H)[lane];
    float d = pw.x * h4.x + pw.y * h4.y + pw.z * h4.z + pw.w * h4.w;
    d = wave_reduce_sum(d);
    if (lane == 0) out[gw] = d + pitch_b[gw];
  }
  if (gw >= 48) {  // dur head rows 0..15 (block 3)
    const int row = gw - 48;
    const float* dw = dur_W + (size_t)row * 266;
    float d = 0.f;
    for (int k = lane; k < 266; k += 64)
      d += dw[k] * (k < 10 ? etsh[k] : hsh[k - 10]);
    d = wave_reduce_sum(d);
    if (lane == 0) out[63 + row] = d + dur_b[row];
  }
}

extern "C" void kernel_launch(void* const* d_in, const int* in_sizes, int n_in,
                              void* d_out, int out_size, void* d_ws, size_t ws_size,
                              hipStream_t stream) {
  const int* sec       = (const int*)d_in[0];
  const int* chord     = (const int*)d_in[1];
  const int* tp        = (const int*)d_in[2];
  const int* note      = (const int*)d_in[3];
  const float* hn      = (const float*)d_in[4];
  const float* cn      = (const float*)d_in[5];
  const float* E       = (const float*)d_in[6];
  const float* chord_e = (const float*)d_in[7];
  const float* pitch_e = (const float*)d_in[8];
  const float* dur_e   = (const float*)d_in[9];
  const float* W_ih    = (const float*)d_in[10];
  const float* W_hh    = (const float*)d_in[11];
  const float* b_ih    = (const float*)d_in[12];
  const float* b_hh    = (const float*)d_in[13];
  const float* pitch_W = (const float*)d_in[14];
  const float* pitch_b = (const float*)d_in[15];
  const float* dur_W   = (const float*)d_in[16];
  const float* dur_b   = (const float*)d_in[17];
  const float* attn_W  = (const float*)d_in[18];
  const float* attn_b  = (const float*)d_in[19];
  float* out = (float*)d_out;
  float* ws = (float*)d_ws;

  float* p10   = ws;                 // 11 * 1024
  float* ghh2  = ws + 11 * NBLK;     // 1024
  float* WcT   = ghh2 + 1024;        // 10 * 1024
  float* dummy = WcT + 10 * NBLK;    // 64

  k1_attn<<<NBLK, 256, 0, stream>>>(E, hn, attn_W, W_hh, b_ih, b_hh, W_ih,
                                    chord_e, pitch_e, dur_e, sec, chord, note,
                                    pitch_W, dur_W, p10, ghh2, WcT, dummy);
  k2_tail<<<4, 1024, 0, stream>>>(p10, ghh2, WcT, attn_b, cn,
                                  pitch_W, pitch_b, dur_W, dur_b,
                                  pitch_e, tp, out);
}